// Round 1
// baseline (326.481 us; speedup 1.0000x reference)
//
#include <hip/hip_runtime.h>

#define N_NODES 50000
#define N_EDGES 800000
#define IN_FEAT 512
#define OUT_FEAT 128

__device__ __forceinline__ float multispike(float a) {
    // floor(clamp(4x, 0, 4) + 0.5) / 4
    return floorf(fminf(fmaxf(4.0f * a, 0.0f), 4.0f) + 0.5f) * 0.25f;
}

// ---------------------------------------------------------------------------
// GEMM: C[M,128] = A[M,512] @ B[512,128], fp32 vector FMA.
// BM=64, BN=128, BK=32. 256 threads. Thread tile 8x4.
// ---------------------------------------------------------------------------
__global__ __launch_bounds__(256) void gemm_kernel(const float* __restrict__ A,
                                                   const float* __restrict__ B,
                                                   float* __restrict__ C, int M) {
    __shared__ float As[32][64];    // [k][m]  (transposed on store)
    __shared__ float Bs[32][128];   // [k][n]

    const int tid = threadIdx.x;
    const int tx = tid & 31;   // n-group: n = tx*4 .. tx*4+3
    const int ty = tid >> 5;   // m-group: m = ty*8 .. ty*8+7
    const int block_m = blockIdx.x * 64;

    float acc[8][4];
#pragma unroll
    for (int i = 0; i < 8; i++)
#pragma unroll
        for (int j = 0; j < 4; j++) acc[i][j] = 0.0f;

    for (int k0 = 0; k0 < IN_FEAT; k0 += 32) {
        // Stage A tile: 64 rows x 32 k. 512 float4 loads / 256 threads = 2 each.
        // flat f: row r = f>>3 (0..63), k-quad kq = (f&7)*4. Coalesced global read,
        // transpose on LDS store (8-way store conflict; negligible vs FMA work).
#pragma unroll
        for (int i = 0; i < 2; i++) {
            int f = tid + i * 256;
            int r = f >> 3;
            int kq = (f & 7) << 2;
            int gm = block_m + r;
            float4 v = make_float4(0.f, 0.f, 0.f, 0.f);
            if (gm < M) v = *(const float4*)(A + (size_t)gm * IN_FEAT + k0 + kq);
            As[kq + 0][r] = v.x;
            As[kq + 1][r] = v.y;
            As[kq + 2][r] = v.z;
            As[kq + 3][r] = v.w;
        }
        // Stage B tile: 32 rows x 128 n = 1024 float4 / 256 threads = 4 each.
#pragma unroll
        for (int i = 0; i < 4; i++) {
            int f = tid + i * 256;
            int r = f >> 5;             // 0..31
            int n4 = (f & 31) << 2;     // 0,4,..,124
            *(float4*)&Bs[r][n4] = *(const float4*)(B + (size_t)(k0 + r) * OUT_FEAT + n4);
        }
        __syncthreads();

#pragma unroll
        for (int k = 0; k < 32; k++) {
            float4 a0 = *(const float4*)&As[k][ty * 8];
            float4 a1 = *(const float4*)&As[k][ty * 8 + 4];
            float4 b = *(const float4*)&Bs[k][tx * 4];
            float av[8] = {a0.x, a0.y, a0.z, a0.w, a1.x, a1.y, a1.z, a1.w};
            float bv[4] = {b.x, b.y, b.z, b.w};
#pragma unroll
            for (int i = 0; i < 8; i++)
#pragma unroll
                for (int j = 0; j < 4; j++)
                    acc[i][j] = fmaf(av[i], bv[j], acc[i][j]);
        }
        __syncthreads();
    }

#pragma unroll
    for (int i = 0; i < 8; i++) {
        int gm = block_m + ty * 8 + i;
        if (gm < M) {
            float4 v = make_float4(acc[i][0], acc[i][1], acc[i][2], acc[i][3]);
            *(float4*)(C + (size_t)gm * OUT_FEAT + tx * 4) = v;
        }
    }
}

// ---------------------------------------------------------------------------
// row_ptr[i] = lower_bound(rows, i) over sorted rows. i in [0, N_NODES].
// ---------------------------------------------------------------------------
__global__ __launch_bounds__(256) void rowptr_kernel(const int* __restrict__ rows,
                                                     int* __restrict__ row_ptr) {
    int i = blockIdx.x * blockDim.x + threadIdx.x;
    if (i > N_NODES) return;
    int lo = 0, hi = N_EDGES;
    while (lo < hi) {
        int mid = (lo + hi) >> 1;
        if (rows[mid] < i) lo = mid + 1; else hi = mid;
    }
    row_ptr[i] = lo;
}

// ---------------------------------------------------------------------------
// SPMM + multispike: one wave per output row. Lane l accumulates features
// l and l+64. Edge gathers are 2x 256B coalesced reads per edge.
// ---------------------------------------------------------------------------
__global__ __launch_bounds__(256) void spmm_kernel(const float* __restrict__ x,
                                                   const int* __restrict__ cols,
                                                   const float* __restrict__ ew,
                                                   const int* __restrict__ row_ptr,
                                                   float* __restrict__ out) {
    const int wave = threadIdx.x >> 6;
    const int lane = threadIdx.x & 63;
    const int r = blockIdx.x * 4 + wave;
    if (r >= N_NODES) return;

    const int e0 = row_ptr[r];
    const int e1 = row_ptr[r + 1];

    float acc0 = 0.0f, acc1 = 0.0f;
    for (int e = e0; e < e1; e++) {
        int c = cols[e];
        float w = ew[e];
        const float* xp = x + (size_t)c * OUT_FEAT;
        acc0 = fmaf(w, xp[lane], acc0);
        acc1 = fmaf(w, xp[lane + 64], acc1);
    }
    out[(size_t)r * OUT_FEAT + lane] = multispike(acc0);
    out[(size_t)r * OUT_FEAT + lane + 64] = multispike(acc1);
}

extern "C" void kernel_launch(void* const* d_in, const int* in_sizes, int n_in,
                              void* d_out, int out_size, void* d_ws, size_t ws_size,
                              hipStream_t stream) {
    const float* feat = (const float*)d_in[0];   // [50000, 512]
    const float* weight = (const float*)d_in[1]; // [512, 128]
    const int* rows = (const int*)d_in[2];       // [800000] sorted
    const int* cols = (const int*)d_in[3];       // [800000]
    const float* ew = (const float*)d_in[4];     // [800000]
    float* out = (float*)d_out;                  // [50000, 128]

    // Workspace layout: x [50000*128 f32] then row_ptr [50001 i32]
    float* x = (float*)d_ws;
    int* row_ptr = (int*)((char*)d_ws + (size_t)N_NODES * OUT_FEAT * sizeof(float));

    rowptr_kernel<<<(N_NODES + 256) / 256, 256, 0, stream>>>(rows, row_ptr);
    gemm_kernel<<<(N_NODES + 63) / 64, 256, 0, stream>>>(feat, weight, x, N_NODES);
    spmm_kernel<<<(N_NODES + 3) / 4, 256, 0, stream>>>(x, cols, ew, row_ptr, out);
}

// Round 2
// 317.453 us; speedup vs baseline: 1.0284x; 1.0284x over previous
//
#include <hip/hip_runtime.h>

#define N_NODES 50000
#define N_EDGES 800000
#define IN_FEAT 512
#define OUT_FEAT 128

__device__ __forceinline__ float multispike(float a) {
    // floor(clamp(4x, 0, 4) + 0.5) / 4
    return floorf(fminf(fmaxf(4.0f * a, 0.0f), 4.0f) + 0.5f) * 0.25f;
}

// ---------------------------------------------------------------------------
// GEMM: C[M,128] = A[M,512] @ B[512,128], fp32 vector FMA.
// BM=64, BN=128, BK=32. 256 threads. Thread tile 8x4.
// Software-pipelined: next K-tile global loads issue before current compute,
// so the vmcnt wait lands at the LDS store AFTER compute (latency hidden).
// As padded to 68 floats/row: transposed-store conflict 8-way -> ~4-way,
// rows stay 16B-aligned (272 B) so b128 reads survive.
// ---------------------------------------------------------------------------
__global__ __launch_bounds__(256) void gemm_kernel(const float* __restrict__ A,
                                                   const float* __restrict__ B,
                                                   float* __restrict__ C, int M) {
    __shared__ float As[32][68];    // [k][m], padded
    __shared__ float Bs[32][128];   // [k][n]

    const int tid = threadIdx.x;
    const int tx = tid & 31;   // n-group: n = tx*4 .. tx*4+3
    const int ty = tid >> 5;   // m-group: m = ty*8 .. ty*8+7
    const int block_m = blockIdx.x * 64;

    // staging decode (A): flat f = tid + i*256; r = f>>3 (0..63), kq = (f&7)*4
    const int a_r0 = tid >> 3;
    const int a_kq = (tid & 7) << 2;
    // staging decode (B): flat f = tid + i*256; r = f>>5 (0..31 over 4 iters), n4 = (f&31)*4
    const int b_n4 = (tid & 31) << 2;
    const int b_r0 = tid >> 5;

    float acc[8][4];
#pragma unroll
    for (int i = 0; i < 8; i++)
#pragma unroll
        for (int j = 0; j < 4; j++) acc[i][j] = 0.0f;

    float4 pa[2];   // prefetched A quads
    float4 pb[4];   // prefetched B quads

    // ---- prologue: prefetch tile 0 ----
    {
        const int k0 = 0;
#pragma unroll
        for (int i = 0; i < 2; i++) {
            int gm = block_m + a_r0 + i * 32;
            pa[i] = make_float4(0.f, 0.f, 0.f, 0.f);
            if (gm < M) pa[i] = *(const float4*)(A + (size_t)gm * IN_FEAT + k0 + a_kq);
        }
#pragma unroll
        for (int i = 0; i < 4; i++) {
            int r = b_r0 + i * 8;
            pb[i] = *(const float4*)(B + (size_t)(k0 + r) * OUT_FEAT + b_n4);
        }
    }

    for (int t = 0; t < IN_FEAT / 32; t++) {
        // store prefetched tile to LDS (vmcnt wait happens here, after the
        // previous tile's compute has already run)
#pragma unroll
        for (int i = 0; i < 2; i++) {
            int r = a_r0 + i * 32;
            As[a_kq + 0][r] = pa[i].x;
            As[a_kq + 1][r] = pa[i].y;
            As[a_kq + 2][r] = pa[i].z;
            As[a_kq + 3][r] = pa[i].w;
        }
#pragma unroll
        for (int i = 0; i < 4; i++) {
            *(float4*)&Bs[b_r0 + i * 8][b_n4] = pb[i];
        }
        __syncthreads();

        // prefetch tile t+1 (global loads in flight during compute below)
        if (t + 1 < IN_FEAT / 32) {
            const int k0 = (t + 1) * 32;
#pragma unroll
            for (int i = 0; i < 2; i++) {
                int gm = block_m + a_r0 + i * 32;
                pa[i] = make_float4(0.f, 0.f, 0.f, 0.f);
                if (gm < M) pa[i] = *(const float4*)(A + (size_t)gm * IN_FEAT + k0 + a_kq);
            }
#pragma unroll
            for (int i = 0; i < 4; i++) {
                int r = b_r0 + i * 8;
                pb[i] = *(const float4*)(B + (size_t)(k0 + r) * OUT_FEAT + b_n4);
            }
        }

        // compute current tile
#pragma unroll
        for (int k = 0; k < 32; k++) {
            float4 a0 = *(const float4*)&As[k][ty * 8];
            float4 a1 = *(const float4*)&As[k][ty * 8 + 4];
            float4 b = *(const float4*)&Bs[k][tx * 4];
            float av[8] = {a0.x, a0.y, a0.z, a0.w, a1.x, a1.y, a1.z, a1.w};
            float bv[4] = {b.x, b.y, b.z, b.w};
#pragma unroll
            for (int i = 0; i < 8; i++)
#pragma unroll
                for (int j = 0; j < 4; j++)
                    acc[i][j] = fmaf(av[i], bv[j], acc[i][j]);
        }
        __syncthreads();
    }

#pragma unroll
    for (int i = 0; i < 8; i++) {
        int gm = block_m + ty * 8 + i;
        if (gm < M) {
            float4 v = make_float4(acc[i][0], acc[i][1], acc[i][2], acc[i][3]);
            *(float4*)(C + (size_t)gm * OUT_FEAT + tx * 4) = v;
        }
    }
}

// ---------------------------------------------------------------------------
// row_ptr[i] = lower_bound(rows, i) over sorted rows. i in [0, N_NODES].
// ---------------------------------------------------------------------------
__global__ __launch_bounds__(256) void rowptr_kernel(const int* __restrict__ rows,
                                                     int* __restrict__ row_ptr) {
    int i = blockIdx.x * blockDim.x + threadIdx.x;
    if (i > N_NODES) return;
    int lo = 0, hi = N_EDGES;
    while (lo < hi) {
        int mid = (lo + hi) >> 1;
        if (rows[mid] < i) lo = mid + 1; else hi = mid;
    }
    row_ptr[i] = lo;
}

// ---------------------------------------------------------------------------
// SPMM + multispike: one wave per output row, lane l owns float2 l.
// Unrolled x4: 4 independent gathers in flight per step (4x MLP on the
// col->gather latency chain).
// ---------------------------------------------------------------------------
__global__ __launch_bounds__(256) void spmm_kernel(const float* __restrict__ x,
                                                   const int* __restrict__ cols,
                                                   const float* __restrict__ ew,
                                                   const int* __restrict__ row_ptr,
                                                   float* __restrict__ out) {
    const int wave = threadIdx.x >> 6;
    const int lane = threadIdx.x & 63;
    const int r = blockIdx.x * 4 + wave;
    if (r >= N_NODES) return;

    const int e0 = row_ptr[r];
    const int e1 = row_ptr[r + 1];
    const float2* __restrict__ x2 = (const float2*)x;

    float accx = 0.0f, accy = 0.0f;
    int e = e0;
    for (; e + 4 <= e1; e += 4) {
        int c0 = cols[e], c1 = cols[e + 1], c2 = cols[e + 2], c3 = cols[e + 3];
        float w0 = ew[e], w1 = ew[e + 1], w2 = ew[e + 2], w3 = ew[e + 3];
        float2 v0 = x2[(size_t)c0 * 64 + lane];
        float2 v1 = x2[(size_t)c1 * 64 + lane];
        float2 v2 = x2[(size_t)c2 * 64 + lane];
        float2 v3 = x2[(size_t)c3 * 64 + lane];
        accx = fmaf(w0, v0.x, accx); accy = fmaf(w0, v0.y, accy);
        accx = fmaf(w1, v1.x, accx); accy = fmaf(w1, v1.y, accy);
        accx = fmaf(w2, v2.x, accx); accy = fmaf(w2, v2.y, accy);
        accx = fmaf(w3, v3.x, accx); accy = fmaf(w3, v3.y, accy);
    }
    for (; e < e1; e++) {
        int c = cols[e];
        float w = ew[e];
        float2 v = x2[(size_t)c * 64 + lane];
        accx = fmaf(w, v.x, accx);
        accy = fmaf(w, v.y, accy);
    }
    float2* out2 = (float2*)out;
    out2[(size_t)r * 64 + lane] = make_float2(multispike(accx), multispike(accy));
}

extern "C" void kernel_launch(void* const* d_in, const int* in_sizes, int n_in,
                              void* d_out, int out_size, void* d_ws, size_t ws_size,
                              hipStream_t stream) {
    const float* feat = (const float*)d_in[0];   // [50000, 512]
    const float* weight = (const float*)d_in[1]; // [512, 128]
    const int* rows = (const int*)d_in[2];       // [800000] sorted
    const int* cols = (const int*)d_in[3];       // [800000]
    const float* ew = (const float*)d_in[4];     // [800000]
    float* out = (float*)d_out;                  // [50000, 128]

    // Workspace layout: x [50000*128 f32] then row_ptr [50001 i32]
    float* x = (float*)d_ws;
    int* row_ptr = (int*)((char*)d_ws + (size_t)N_NODES * OUT_FEAT * sizeof(float));

    rowptr_kernel<<<(N_NODES + 256) / 256, 256, 0, stream>>>(rows, row_ptr);
    gemm_kernel<<<(N_NODES + 63) / 64, 256, 0, stream>>>(feat, weight, x, N_NODES);
    spmm_kernel<<<(N_NODES + 3) / 4, 256, 0, stream>>>(x, cols, ew, row_ptr, out);
}

// Round 4
// 316.227 us; speedup vs baseline: 1.0324x; 1.0039x over previous
//
#include <hip/hip_runtime.h>

#define N_NODES 50000
#define N_EDGES 800000
#define IN_FEAT 512
#define OUT_FEAT 128

// NUMERICS CONTRACT (R3 post-mortem): the harness's np reference is matched
// bit-for-bit through the multispike quantizer ONLY when fp32 accumulation
// order is strictly sequential (k-order in GEMM, edge-order in SPMM).
// Reassociating a sum (R3's even/odd edge split) flipped a floor() boundary
// -> absmax 0.25. Do NOT split accumulator chains; get MLP from batched
// independent loads feeding ONE in-order FMA chain.

__device__ __forceinline__ float multispike(float a) {
    // floor(clamp(4x, 0, 4) + 0.5) / 4
    return floorf(fminf(fmaxf(4.0f * a, 0.0f), 4.0f) + 0.5f) * 0.25f;
}

// ---------------------------------------------------------------------------
// GEMM: C[M,128] = A[M,512] @ B[512,128], fp32 vector FMA.
// BM=64, BN=128, BK=32. 128 threads (2 waves). Thread tile 8x8.
// - 8x8 tile: 4 ds_read_b128 per 64 FMAs (R2 showed the 8x4 kernel was
//   LDS-pipe-bound at 3 reads per 32 FMAs).
// - No explicit global prefetch (R2: regressed; implicit wave overlap at
//   ~6 blocks/CU hides staging).
// - As padded to 68: transposed-store 8-way conflict -> 4-way, rows stay
//   16B-aligned for b128 reads. A-reads conflict-free (ty in 0..3 per wave).
// - Bs XOR quad-swizzle pq = q ^ ((q>>3)&1): B-read addresses tx*32B alias
//   banks at 128B stride (4-way); swizzle makes them 2-way = free (m136).
//   Pure storage permutation, same map on store and load.
// ---------------------------------------------------------------------------
__device__ __forceinline__ int bswz(int q) { return q ^ ((q >> 3) & 1); }

__global__ __launch_bounds__(128) void gemm_kernel(const float* __restrict__ A,
                                                   const float* __restrict__ B,
                                                   float* __restrict__ C, int M) {
    __shared__ float As[32][68];    // [k][m], padded
    __shared__ float Bs[32][128];   // [k][n], quad-swizzled

    const int tid = threadIdx.x;
    const int tx = tid & 15;   // n0 = tx*8
    const int ty = tid >> 4;   // m0 = ty*8  (0..7)
    const int block_m = blockIdx.x * 64;

    // read-side physical quads for this thread's two B float4s
    const int bq0 = bswz(2 * tx) * 4;
    const int bq1 = bswz(2 * tx + 1) * 4;

    float acc[8][8];
#pragma unroll
    for (int i = 0; i < 8; i++)
#pragma unroll
        for (int j = 0; j < 8; j++) acc[i][j] = 0.0f;

    for (int k0 = 0; k0 < IN_FEAT; k0 += 32) {
        // Stage A tile: 64 rows x 32 k = 512 float4 / 128 threads = 4 each.
#pragma unroll
        for (int i = 0; i < 4; i++) {
            int f = tid + i * 128;
            int r = f >> 3;
            int kq = (f & 7) << 2;
            int gm = block_m + r;
            float4 v = make_float4(0.f, 0.f, 0.f, 0.f);
            if (gm < M) v = *(const float4*)(A + (size_t)gm * IN_FEAT + k0 + kq);
            As[kq + 0][r] = v.x;
            As[kq + 1][r] = v.y;
            As[kq + 2][r] = v.z;
            As[kq + 3][r] = v.w;
        }
        // Stage B tile: 32 rows x 128 n = 1024 float4 / 128 threads = 8 each.
        // Store at swizzled quad position.
#pragma unroll
        for (int i = 0; i < 8; i++) {
            int f = tid + i * 128;
            int r = f >> 5;             // 0..31
            int q = f & 31;             // logical quad 0..31
            *(float4*)&Bs[r][bswz(q) * 4] =
                *(const float4*)(B + (size_t)(k0 + r) * OUT_FEAT + q * 4);
        }
        __syncthreads();

#pragma unroll
        for (int k = 0; k < 32; k++) {
            float4 a0 = *(const float4*)&As[k][ty * 8];
            float4 a1 = *(const float4*)&As[k][ty * 8 + 4];
            float4 b0 = *(const float4*)&Bs[k][bq0];
            float4 b1 = *(const float4*)&Bs[k][bq1];
            float av[8] = {a0.x, a0.y, a0.z, a0.w, a1.x, a1.y, a1.z, a1.w};
            float bv[8] = {b0.x, b0.y, b0.z, b0.w, b1.x, b1.y, b1.z, b1.w};
#pragma unroll
            for (int i = 0; i < 8; i++)
#pragma unroll
                for (int j = 0; j < 8; j++)
                    acc[i][j] = fmaf(av[i], bv[j], acc[i][j]);
        }
        __syncthreads();
    }

#pragma unroll
    for (int i = 0; i < 8; i++) {
        int gm = block_m + ty * 8 + i;
        if (gm < M) {
            float* cp = C + (size_t)gm * OUT_FEAT + tx * 8;
            *(float4*)cp = make_float4(acc[i][0], acc[i][1], acc[i][2], acc[i][3]);
            *(float4*)(cp + 4) = make_float4(acc[i][4], acc[i][5], acc[i][6], acc[i][7]);
        }
    }
}

// ---------------------------------------------------------------------------
// row_ptr[i] = lower_bound(rows, i) over sorted rows. i in [0, N_NODES].
// ---------------------------------------------------------------------------
__global__ __launch_bounds__(256) void rowptr_kernel(const int* __restrict__ rows,
                                                     int* __restrict__ row_ptr) {
    int i = blockIdx.x * blockDim.x + threadIdx.x;
    if (i > N_NODES) return;
    int lo = 0, hi = N_EDGES;
    while (lo < hi) {
        int mid = (lo + hi) >> 1;
        if (rows[mid] < i) lo = mid + 1; else hi = mid;
    }
    row_ptr[i] = lo;
}

// ---------------------------------------------------------------------------
// SPMM + multispike: one wave per output row, lane l owns float2 l of the
// 128-float row. Unroll x8: 8 independent gathers issued per step (MLP),
// then ONE in-order FMA chain per accumulator -> summation order identical
// to the reference edge order (see NUMERICS CONTRACT above).
// ---------------------------------------------------------------------------
__global__ __launch_bounds__(256) void spmm_kernel(const float* __restrict__ x,
                                                   const int* __restrict__ cols,
                                                   const float* __restrict__ ew,
                                                   const int* __restrict__ row_ptr,
                                                   float* __restrict__ out) {
    const int wave = threadIdx.x >> 6;
    const int lane = threadIdx.x & 63;
    const int r = blockIdx.x * 4 + wave;
    if (r >= N_NODES) return;

    const int e0 = row_ptr[r];
    const int e1 = row_ptr[r + 1];
    const float2* __restrict__ x2 = (const float2*)x;

    float accx = 0.0f, accy = 0.0f;
    int e = e0;
    for (; e + 8 <= e1; e += 8) {
        int c[8];
        float w[8];
        float2 v[8];
#pragma unroll
        for (int j = 0; j < 8; j++) {
            c[j] = cols[e + j];
            w[j] = ew[e + j];
        }
#pragma unroll
        for (int j = 0; j < 8; j++) {
            v[j] = x2[(size_t)c[j] * 64 + lane];
        }
#pragma unroll
        for (int j = 0; j < 8; j++) {   // strict e-order accumulation
            accx = fmaf(w[j], v[j].x, accx);
            accy = fmaf(w[j], v[j].y, accy);
        }
    }
    for (; e < e1; e++) {
        int c = cols[e];
        float w = ew[e];
        float2 v = x2[(size_t)c * 64 + lane];
        accx = fmaf(w, v.x, accx);
        accy = fmaf(w, v.y, accy);
    }
    float2* out2 = (float2*)out;
    out2[(size_t)r * 64 + lane] = make_float2(multispike(accx), multispike(accy));
}

extern "C" void kernel_launch(void* const* d_in, const int* in_sizes, int n_in,
                              void* d_out, int out_size, void* d_ws, size_t ws_size,
                              hipStream_t stream) {
    const float* feat = (const float*)d_in[0];   // [50000, 512]
    const float* weight = (const float*)d_in[1]; // [512, 128]
    const int* rows = (const int*)d_in[2];       // [800000] sorted
    const int* cols = (const int*)d_in[3];       // [800000]
    const float* ew = (const float*)d_in[4];     // [800000]
    float* out = (float*)d_out;                  // [50000, 128]

    // Workspace layout: x [50000*128 f32] then row_ptr [50001 i32]
    float* x = (float*)d_ws;
    int* row_ptr = (int*)((char*)d_ws + (size_t)N_NODES * OUT_FEAT * sizeof(float));

    rowptr_kernel<<<(N_NODES + 256) / 256, 256, 0, stream>>>(rows, row_ptr);
    gemm_kernel<<<(N_NODES + 63) / 64, 128, 0, stream>>>(feat, weight, x, N_NODES);
    spmm_kernel<<<(N_NODES + 3) / 4, 256, 0, stream>>>(x, cols, ew, row_ptr, out);
}